// Round 2
// baseline (991.656 us; speedup 1.0000x reference)
//
#include <hip/hip_runtime.h>

// NeuralODE via state reformulation: track z = x@W1 + b1 instead of x.
//   h1 = tanh(z)                       (element-wise, in registers -> no L1 MFMA)
//   h2 = tanh(h1 @ W2 + b2)            (MFMA K=256)
//   z' = z + h2 @ (s*W3@W1) + s*b3@W1  (MFMA K=256, C-init = z  -> Euler folded)
//   x' = x + h2 @ (s*W3)    + s*b3     (MFMA K=256, C-init = x, waves 4-7, traj store)
// 2 raw barriers/step (lgkmcnt-only waits, no vmcnt drain of trajectory stores).
// BATCH=4096, STATE=64, HIDDEN=256, steps=200. Output [4096, 201, 64] fp32.

#define TILE_M 16
#define NBLK   256
#define XPITCH 68      // bf16 x pitch (shorts), init only
#define HPITCH 260     // bf16 h pitch (shorts): quads land on distinct banks

typedef short v8s __attribute__((ext_vector_type(8)));
typedef float v4f __attribute__((ext_vector_type(4)));

__device__ __forceinline__ unsigned short f2bf(float f) {
    return (unsigned short)((__float_as_uint(f) + 0x8000u) >> 16);  // round-half-up
}
__device__ __forceinline__ unsigned cvt_pk_bf16(float a, float b) {
    unsigned r;
    asm("v_cvt_pk_bf16_f32 %0, %1, %2" : "=v"(r) : "v"(a), "v"(b));
    return r;
}
__device__ __forceinline__ float fast_tanh(float x) {
    float e = __builtin_amdgcn_exp2f(x * 2.8853900817779268f);  // exp(2x)
    return 1.0f - 2.0f * __builtin_amdgcn_rcpf(e + 1.0f);
}
// Raw barrier: LDS visibility only. Trajectory stores are never vmcnt-drained
// in-loop (nobody reads 'out'; dispatch-end completion handles them).
__device__ __forceinline__ void sync_lds() {
    asm volatile("s_waitcnt lgkmcnt(0)" ::: "memory");
    __builtin_amdgcn_s_barrier();
    asm volatile("" ::: "memory");
}

// ---- prep 1: transposes to [N][K] bf16; W3 pre-scaled by dt ----
__global__ void prep_weights(const float* __restrict__ W1,
                             const float* __restrict__ W2,
                             const float* __restrict__ W3,
                             const float* __restrict__ dt_scale,
                             short* __restrict__ W1t,    // [256][64]
                             short* __restrict__ W2t,    // [256][256]
                             short* __restrict__ W3ts) { // [64][256], * scale
    int u = blockIdx.x * 256 + threadIdx.x;
    if (u < 65536) {                       // W2t[n][k] = W2[k][n]
        int n = u >> 8, k = u & 255;
        W2t[u] = (short)f2bf(W2[k * 256 + n]);
    }
    int v = u - 65536;
    if (v >= 0 && v < 16384) {             // W1t[n][k] = W1[k][n]
        int n = v >> 6, k = v & 63;
        W1t[v] = (short)f2bf(W1[k * 256 + n]);
    }
    int t = u - (65536 + 16384);
    if (t >= 0 && t < 16384) {             // W3ts[n][k] = scale * W3[k][n]
        float scale = dt_scale[0] * 0.01f;
        int n = t >> 8, k = t & 255;
        W3ts[t] = (short)f2bf(W3[k * 64 + n] * scale);
    }
}

// ---- prep 2: W31t[n][k] = scale * sum_j W3[k][j] W1[j][n];  bW1s[n] = scale * b3@W1 ----
// block k: W3 row uniform (scalar loads), W1 row coalesced across threads n.
__global__ void prep_w31(const float* __restrict__ W1,
                         const float* __restrict__ W3,
                         const float* __restrict__ b3,
                         const float* __restrict__ dt_scale,
                         short* __restrict__ W31t,   // [256][256]
                         float* __restrict__ bW1s) { // [256]
    int k = blockIdx.x;
    int n = threadIdx.x;
    float scale = dt_scale[0] * 0.01f;
    if (k < 256) {
        float acc = 0.f;
        #pragma unroll 8
        for (int j = 0; j < 64; j++)
            acc = fmaf(W3[k * 64 + j], W1[j * 256 + n], acc);
        W31t[n * 256 + k] = (short)f2bf(acc * scale);
    } else {                               // block 256: bias product
        float acc = 0.f;
        #pragma unroll 8
        for (int j = 0; j < 64; j++)
            acc = fmaf(b3[j], W1[j * 256 + n], acc);
        bW1s[n] = acc * scale;
    }
}

__global__ __launch_bounds__(512, 2)
void ode_kernel(const float* __restrict__ x0,
                const float* __restrict__ b1,
                const float* __restrict__ b2,
                const float* __restrict__ b3,
                const float* __restrict__ dt_scale,
                const int*   __restrict__ stepsp,
                const short* __restrict__ W1t,
                const short* __restrict__ W2t,
                const short* __restrict__ W3ts,
                const short* __restrict__ W31t,
                const float* __restrict__ bW1s,
                float* __restrict__ out) {
    __shared__ short h1b[TILE_M * HPITCH];
    __shared__ short h2b[TILE_M * HPITCH];
    __shared__ short xb [TILE_M * XPITCH];   // init only

    const int tid  = threadIdx.x;
    const int w    = tid >> 6;        // wave 0..7
    const int lane = tid & 63;
    const int ln   = lane & 15;       // batch row (B col / C col)
    const int q    = lane >> 4;
    const int blk  = blockIdx.x;
    const int nsteps = *stepsp;
    const int n0 = 32 * w;            // this wave's 32 hidden features (h2 & z)
    const bool xw = (w >= 4);         // waves 4-7 own the x / trajectory path
    const int t3 = w & 3;             // x tile for waves 4-7

    // ---- weight A-fragments (A[m=ln][k=32ks+8q+j]) ----
    v8s w2f[2][8], w31f[2][8], w3f[8];
    #pragma unroll
    for (int t = 0; t < 2; t++)
        #pragma unroll
        for (int ks = 0; ks < 8; ks++) {
            w2f [t][ks] = *(const v8s*)(W2t  + (n0 + 16 * t + ln) * 256 + 32 * ks + 8 * q);
            w31f[t][ks] = *(const v8s*)(W31t + (n0 + 16 * t + ln) * 256 + 32 * ks + 8 * q);
        }
    if (xw) {
        #pragma unroll
        for (int ks = 0; ks < 8; ks++)
            w3f[ks] = *(const v8s*)(W3ts + (16 * t3 + ln) * 256 + 32 * ks + 8 * q);
    }

    // ---- biases as per-lane float4 (C rows = feats 4q+i) ----
    v4f b2v[2], bzv[2], b3s = {0.f, 0.f, 0.f, 0.f};
    #pragma unroll
    for (int t = 0; t < 2; t++) {
        b2v[t] = *(const v4f*)(b2   + n0 + 16 * t + 4 * q);
        bzv[t] = *(const v4f*)(bW1s + n0 + 16 * t + 4 * q);
    }
    const float scale = dt_scale[0] * 0.01f;
    if (xw) {
        v4f bt = *(const v4f*)(b3 + 16 * t3 + 4 * q);
        b3s = bt * scale;
    }

    // ---- x state (waves 4-7), trajectory sample 0, x0 -> xb for z-init ----
    v4f x = {0.f, 0.f, 0.f, 0.f};
    unsigned tbase = 0;
    if (xw) {
        x = *(const v4f*)(x0 + (size_t)(blk * TILE_M + ln) * 64 + 16 * t3 + 4 * q);
        uint2 p; p.x = cvt_pk_bf16(x[0], x[1]); p.y = cvt_pk_bf16(x[2], x[3]);
        *(uint2*)(xb + ln * XPITCH + 16 * t3 + 4 * q) = p;
        tbase = (unsigned)(blk * TILE_M + ln) * (unsigned)((nsteps + 1) * 64)
              + 16 * t3 + 4 * q;
        *(v4f*)(out + tbase) = x;
        tbase += 64;
    }
    sync_lds();

    // ---- z init: z = x0 @ W1 + b1 (K=64) ----
    v4f z0, z1;
    {
        v8s xa0 = *(const v8s*)(xb + ln * XPITCH + 8 * q);
        v8s xa1 = *(const v8s*)(xb + ln * XPITCH + 32 + 8 * q);
        v8s w1a[2][2];
        #pragma unroll
        for (int t = 0; t < 2; t++)
            #pragma unroll
            for (int ks = 0; ks < 2; ks++)
                w1a[t][ks] = *(const v8s*)(W1t + (n0 + 16 * t + ln) * 64 + 32 * ks + 8 * q);
        z0 = *(const v4f*)(b1 + n0 + 4 * q);
        z1 = *(const v4f*)(b1 + n0 + 16 + 4 * q);
        z0 = __builtin_amdgcn_mfma_f32_16x16x32_bf16(w1a[0][0], xa0, z0, 0, 0, 0);
        z1 = __builtin_amdgcn_mfma_f32_16x16x32_bf16(w1a[1][0], xa0, z1, 0, 0, 0);
        z0 = __builtin_amdgcn_mfma_f32_16x16x32_bf16(w1a[0][1], xa1, z0, 0, 0, 0);
        z1 = __builtin_amdgcn_mfma_f32_16x16x32_bf16(w1a[1][1], xa1, z1, 0, 0, 0);
    }

    // ---- hoisted LDS pointers (compiler folds +32*ks into ds_read offsets) ----
    const short* hr1 = h1b + ln * HPITCH + 8 * q;
    const short* hr2 = h2b + ln * HPITCH + 8 * q;
    short* hw1 = h1b + ln * HPITCH + n0 + 4 * q;
    short* hw2 = h2b + ln * HPITCH + n0 + 4 * q;

    // ---- A0: h1 = tanh(z) -> h1b ----
    {
        uint2 p0, p1;
        p0.x = cvt_pk_bf16(fast_tanh(z0[0]), fast_tanh(z0[1]));
        p0.y = cvt_pk_bf16(fast_tanh(z0[2]), fast_tanh(z0[3]));
        p1.x = cvt_pk_bf16(fast_tanh(z1[0]), fast_tanh(z1[1]));
        p1.y = cvt_pk_bf16(fast_tanh(z1[2]), fast_tanh(z1[3]));
        *(uint2*)(hw1)      = p0;
        *(uint2*)(hw1 + 16) = p1;
    }
    sync_lds();

    for (int s = 0; s < nsteps; s++) {
        // ---- B: h2 = tanh(h1 @ W2 + b2) -- split 4+4 accumulator chains ----
        v8s ha[8];
        #pragma unroll
        for (int ks = 0; ks < 8; ks++) ha[ks] = *(const v8s*)(hr1 + 32 * ks);
        v4f a0 = b2v[0], a1 = b2v[1];
        v4f c0 = {0.f, 0.f, 0.f, 0.f}, c1 = {0.f, 0.f, 0.f, 0.f};
        #pragma unroll
        for (int ks = 0; ks < 4; ks++) {
            a0 = __builtin_amdgcn_mfma_f32_16x16x32_bf16(w2f[0][ks],     ha[ks],     a0, 0, 0, 0);
            a1 = __builtin_amdgcn_mfma_f32_16x16x32_bf16(w2f[1][ks],     ha[ks],     a1, 0, 0, 0);
            c0 = __builtin_amdgcn_mfma_f32_16x16x32_bf16(w2f[0][ks + 4], ha[ks + 4], c0, 0, 0, 0);
            c1 = __builtin_amdgcn_mfma_f32_16x16x32_bf16(w2f[1][ks + 4], ha[ks + 4], c1, 0, 0, 0);
        }
        a0 += c0; a1 += c1;
        {
            uint2 p0, p1;
            p0.x = cvt_pk_bf16(fast_tanh(a0[0]), fast_tanh(a0[1]));
            p0.y = cvt_pk_bf16(fast_tanh(a0[2]), fast_tanh(a0[3]));
            p1.x = cvt_pk_bf16(fast_tanh(a1[0]), fast_tanh(a1[1]));
            p1.y = cvt_pk_bf16(fast_tanh(a1[2]), fast_tanh(a1[3]));
            *(uint2*)(hw2)      = p0;
            *(uint2*)(hw2 + 16) = p1;
        }
        sync_lds();

        // ---- C: z += h2@W31' + bzv ; x += h2@W3' + b3s (shared h2 frags) ----
        v8s hc[8];
        #pragma unroll
        for (int ks = 0; ks < 8; ks++) hc[ks] = *(const v8s*)(hr2 + 32 * ks);
        v4f p0 = bzv[0], p1 = bzv[1];
        #pragma unroll
        for (int ks = 0; ks < 4; ks++) {
            z0 = __builtin_amdgcn_mfma_f32_16x16x32_bf16(w31f[0][ks],     hc[ks],     z0, 0, 0, 0);
            z1 = __builtin_amdgcn_mfma_f32_16x16x32_bf16(w31f[1][ks],     hc[ks],     z1, 0, 0, 0);
            p0 = __builtin_amdgcn_mfma_f32_16x16x32_bf16(w31f[0][ks + 4], hc[ks + 4], p0, 0, 0, 0);
            p1 = __builtin_amdgcn_mfma_f32_16x16x32_bf16(w31f[1][ks + 4], hc[ks + 4], p1, 0, 0, 0);
        }
        z0 += p0; z1 += p1;
        if (xw) {
            v4f xa = x, xc = b3s;
            #pragma unroll
            for (int ks = 0; ks < 4; ks++) {
                xa = __builtin_amdgcn_mfma_f32_16x16x32_bf16(w3f[ks],     hc[ks],     xa, 0, 0, 0);
                xc = __builtin_amdgcn_mfma_f32_16x16x32_bf16(w3f[ks + 4], hc[ks + 4], xc, 0, 0, 0);
            }
            x = xa + xc;
            *(v4f*)(out + tbase) = x;      // background store, never drained in-loop
            tbase += 64;
        }

        // ---- A: h1 = tanh(z) -> h1b (h1b readers drained at prev sync) ----
        {
            uint2 q0, q1;
            q0.x = cvt_pk_bf16(fast_tanh(z0[0]), fast_tanh(z0[1]));
            q0.y = cvt_pk_bf16(fast_tanh(z0[2]), fast_tanh(z0[3]));
            q1.x = cvt_pk_bf16(fast_tanh(z1[0]), fast_tanh(z1[1]));
            q1.y = cvt_pk_bf16(fast_tanh(z1[2]), fast_tanh(z1[3]));
            *(uint2*)(hw1)      = q0;
            *(uint2*)(hw1 + 16) = q1;
        }
        sync_lds();
    }
}

extern "C" void kernel_launch(void* const* d_in, const int* in_sizes, int n_in,
                              void* d_out, int out_size, void* d_ws, size_t ws_size,
                              hipStream_t stream) {
    const float* x0 = (const float*)d_in[0];
    const float* W1 = (const float*)d_in[1];
    const float* b1 = (const float*)d_in[2];
    const float* W2 = (const float*)d_in[3];
    const float* b2 = (const float*)d_in[4];
    const float* W3 = (const float*)d_in[5];
    const float* b3 = (const float*)d_in[6];
    const float* dt = (const float*)d_in[7];
    const int* steps = (const int*)d_in[8];

    short* W1t  = (short*)d_ws;           // 16384 bf16
    short* W2t  = W1t + 64 * 256;         // 65536 bf16
    short* W3ts = W2t + 256 * 256;        // 16384 bf16 (dt-scaled)
    short* W31t = W3ts + 64 * 256;        // 65536 bf16 (dt-scaled W3@W1)
    float* bW1s = (float*)(W31t + 256 * 256);  // 256 f32

    prep_weights<<<384, 256, 0, stream>>>(W1, W2, W3, dt, W1t, W2t, W3ts);
    prep_w31<<<257, 256, 0, stream>>>(W1, W3, b3, dt, W31t, bW1s);
    ode_kernel<<<NBLK, 512, 0, stream>>>(x0, b1, b2, b3, dt, steps,
                                         W1t, W2t, W3ts, W31t, bW1s,
                                         (float*)d_out);
}

// Round 3
// 454.697 us; speedup vs baseline: 2.1809x; 2.1809x over previous
//
#include <hip/hip_runtime.h>

// NeuralODE: x_{s+1} = x + (tanh(tanh(x W1 + b1) W2 + b2) W3 + b3) * dt_scale * DT
// BATCH=4096, STATE=64, HIDDEN=256, steps=200. Output [4096, 201, 64] fp32.
//
// R6 = proven R4 skeleton (operand-swapped MFMA, weights-in-registers, x-state
// in waves 0-3, __syncthreads everywhere, integer bf16 pack) plus:
//   (1) trajectory samples staged in LDS fp32, flushed every 4 steps as
//       fully-coalesced dwordx4 stores (store-drain off the L3 critical path,
//       4x fewer vmcnt drains, full-line writes);
//   (2) L2/L3 8-deep dependent MFMA accumulator chains split 4+4 (ILP).

#define STATE_DIM 64
#define HIDDEN    256
#define TILE_M    16
#define NBLK      256
#define XPITCH    68      // bf16 x pitch (shorts): mult of 4, non-pow2 banking
#define HPITCH    260     // bf16 h pitch (shorts): quads land on distinct banks
#define TPITCH    68      // fp32 traj row pitch (floats): 2-way banking on writes

typedef short v8s __attribute__((ext_vector_type(8)));
typedef float v4f __attribute__((ext_vector_type(4)));

__device__ __forceinline__ unsigned short f2bf(float f) {
    return (unsigned short)((__float_as_uint(f) + 0x8000u) >> 16);  // round-half-up
}
__device__ __forceinline__ unsigned pk2bf(float a, float b) {
    return ((__float_as_uint(a) + 0x8000u) >> 16) |
           ((__float_as_uint(b) + 0x8000u) & 0xffff0000u);
}
__device__ __forceinline__ float fast_tanh(float x) {
    float e = __builtin_amdgcn_exp2f(x * 2.8853900817779268f);  // exp(2x)
    return 1.0f - 2.0f * __builtin_amdgcn_rcpf(e + 1.0f);
}

// ---- prep: fp32 weights -> bf16, transposed to [N][K] ----
__global__ void prep_weights(const float* __restrict__ W1,
                             const float* __restrict__ W2,
                             const float* __restrict__ W3,
                             short* __restrict__ W1t,   // [256][64]
                             short* __restrict__ W2t,   // [256][256]
                             short* __restrict__ W3t) { // [64][256]
    int u = blockIdx.x * 256 + threadIdx.x;
    if (u < 65536) {                       // W2t[n][k] = W2[k][n]
        int n = u >> 8, k = u & 255;
        W2t[u] = (short)f2bf(W2[k * 256 + n]);
    }
    int v = u - 65536;
    if (v >= 0 && v < 16384) {             // W1t[n][k] = W1[k][n]
        int n = v >> 6, k = v & 63;
        W1t[v] = (short)f2bf(W1[k * 256 + n]);
    }
    int t = u - (65536 + 16384);
    if (t >= 0 && t < 16384) {             // W3t[n][k] = W3[k][n]
        int n = t >> 8, k = t & 255;
        W3t[t] = (short)f2bf(W3[k * 64 + n]);
    }
}

__global__ __launch_bounds__(512, 2)
void ode_kernel(const float* __restrict__ x0,
                const float* __restrict__ b1,
                const float* __restrict__ b2,
                const float* __restrict__ b3,
                const float* __restrict__ dt_scale,
                const int*   __restrict__ stepsp,
                const short* __restrict__ W1t,
                const short* __restrict__ W2t,
                const short* __restrict__ W3t,
                float* __restrict__ out) {
    __shared__ short xb [TILE_M * XPITCH];    // bf16 x, B-operand source
    __shared__ short h1b[TILE_M * HPITCH];
    __shared__ short h2b[TILE_M * HPITCH];
    __shared__ float tb [4][TILE_M][TPITCH];  // staged trajectory (fp32)

    const int tid  = threadIdx.x;
    const int w    = tid >> 6;        // wave 0..7
    const int lane = tid & 63;
    const int ln   = lane & 15;       // batch row (B col / C col)
    const int q    = lane >> 4;
    const int blk  = blockIdx.x;
    const int nsteps = *stepsp;
    const float scale = dt_scale[0] * 0.01f;
    const int n0 = 32 * w;            // this wave's 32 output features (L1/L2)

    // ---- weight A-fragments in registers (A[m=ln][k=32ks+8q+j]) ----
    v8s w1f[2][2], w2f[2][8], w3f[8];
    #pragma unroll
    for (int t = 0; t < 2; t++)
        #pragma unroll
        for (int ks = 0; ks < 2; ks++)
            w1f[t][ks] = *(const v8s*)(W1t + (n0 + 16 * t + ln) * 64 + 32 * ks + 8 * q);
    #pragma unroll
    for (int t = 0; t < 2; t++)
        #pragma unroll
        for (int ks = 0; ks < 8; ks++)
            w2f[t][ks] = *(const v8s*)(W2t + (n0 + 16 * t + ln) * 256 + 32 * ks + 8 * q);
    if (w < 4) {
        #pragma unroll
        for (int ks = 0; ks < 8; ks++)
            w3f[ks] = *(const v8s*)(W3t + (16 * w + ln) * 256 + 32 * ks + 8 * q);
    }
    // ---- biases as per-lane float4 (C rows = feats 4q+i) ----
    v4f b1v[2], b2v[2], b3v = {0.f, 0.f, 0.f, 0.f};
    #pragma unroll
    for (int t = 0; t < 2; t++) {
        b1v[t] = *(const v4f*)(b1 + n0 + 16 * t + 4 * q);
        b2v[t] = *(const v4f*)(b2 + n0 + 16 * t + 4 * q);
    }
    if (w < 4) b3v = *(const v4f*)(b3 + 16 * w + 4 * q);

    // ---- flush mapping: 512 threads cover 16 rows x 4 steps x 64 feats ----
    const unsigned ns1x64 = (unsigned)(nsteps + 1) * 64u;
    const int fr = tid >> 5;            // row 0..15
    const int fu = tid & 31;
    const int fk = fu >> 3;             // step-in-group 0..3
    const int ff = (fu & 7) * 8;        // feature start (8 floats per thread)
    const unsigned gflush = (unsigned)(blk * TILE_M + fr) * ns1x64
                          + (unsigned)(fk + 1) * 64u + (unsigned)ff;
    const float* trd = &tb[fk][fr][ff];

    // ---- x state in registers of waves 0-3: feats 16w+4q+i, batch ln ----
    v4f x = {0.f, 0.f, 0.f, 0.f};
    const int xw0 = ln * XPITCH + 16 * w + 4 * q;
    if (w < 4) {
        x = *(const v4f*)(x0 + (size_t)(blk * TILE_M + ln) * STATE_DIM + 16 * w + 4 * q);
        uint2 p; p.x = pk2bf(x[0], x[1]); p.y = pk2bf(x[2], x[3]);
        *(uint2*)(xb + xw0) = p;
        // trajectory sample 0 (direct store, drained at first barrier)
        unsigned t0 = (unsigned)(blk * TILE_M + ln) * ns1x64 + 16 * w + 4 * q;
        *(v4f*)(out + t0) = x;
    }
    __syncthreads();

    // ---- hoisted LDS indices ----
    int xrd[2], hrd[8];
    #pragma unroll
    for (int ks = 0; ks < 2; ks++) xrd[ks] = ln * XPITCH + 32 * ks + 8 * q;
    #pragma unroll
    for (int ks = 0; ks < 8; ks++) hrd[ks] = ln * HPITCH + 32 * ks + 8 * q;
    const int hw0 = ln * HPITCH + n0 + 4 * q;   // + 16*t for tile t

    for (int s = 0; s < nsteps; s++) {
        // ---- L1: h1 = tanh(x @ W1 + b1)  (A=W1 frags, B=xb) ----
        v8s xa0 = *(const v8s*)(xb + xrd[0]);
        v8s xa1 = *(const v8s*)(xb + xrd[1]);
        v4f a0 = b1v[0], a1 = b1v[1];
        a0 = __builtin_amdgcn_mfma_f32_16x16x32_bf16(w1f[0][0], xa0, a0, 0, 0, 0);
        a1 = __builtin_amdgcn_mfma_f32_16x16x32_bf16(w1f[1][0], xa0, a1, 0, 0, 0);
        a0 = __builtin_amdgcn_mfma_f32_16x16x32_bf16(w1f[0][1], xa1, a0, 0, 0, 0);
        a1 = __builtin_amdgcn_mfma_f32_16x16x32_bf16(w1f[1][1], xa1, a1, 0, 0, 0);
        {
            uint2 p0, p1;
            p0.x = pk2bf(fast_tanh(a0[0]), fast_tanh(a0[1]));
            p0.y = pk2bf(fast_tanh(a0[2]), fast_tanh(a0[3]));
            p1.x = pk2bf(fast_tanh(a1[0]), fast_tanh(a1[1]));
            p1.y = pk2bf(fast_tanh(a1[2]), fast_tanh(a1[3]));
            *(uint2*)(h1b + hw0)      = p0;
            *(uint2*)(h1b + hw0 + 16) = p1;
        }
        __syncthreads();

        // ---- L2: h2 = tanh(h1 @ W2 + b2) -- 4+4 split accumulator chains ----
        v8s ha[8];
        #pragma unroll
        for (int ks = 0; ks < 8; ks++) ha[ks] = *(const v8s*)(h1b + hrd[ks]);
        a0 = b2v[0]; a1 = b2v[1];
        v4f c0 = {0.f, 0.f, 0.f, 0.f}, c1 = {0.f, 0.f, 0.f, 0.f};
        #pragma unroll
        for (int ks = 0; ks < 4; ks++) {
            a0 = __builtin_amdgcn_mfma_f32_16x16x32_bf16(w2f[0][ks],     ha[ks],     a0, 0, 0, 0);
            a1 = __builtin_amdgcn_mfma_f32_16x16x32_bf16(w2f[1][ks],     ha[ks],     a1, 0, 0, 0);
            c0 = __builtin_amdgcn_mfma_f32_16x16x32_bf16(w2f[0][ks + 4], ha[ks + 4], c0, 0, 0, 0);
            c1 = __builtin_amdgcn_mfma_f32_16x16x32_bf16(w2f[1][ks + 4], ha[ks + 4], c1, 0, 0, 0);
        }
        a0 += c0; a1 += c1;
        {
            uint2 p0, p1;
            p0.x = pk2bf(fast_tanh(a0[0]), fast_tanh(a0[1]));
            p0.y = pk2bf(fast_tanh(a0[2]), fast_tanh(a0[3]));
            p1.x = pk2bf(fast_tanh(a1[0]), fast_tanh(a1[1]));
            p1.y = pk2bf(fast_tanh(a1[2]), fast_tanh(a1[3]));
            *(uint2*)(h2b + hw0)      = p0;
            *(uint2*)(h2b + hw0 + 16) = p1;
        }
        __syncthreads();

        // ---- L3 + Euler (waves 0-3): 4+4 split; traj -> LDS stage ----
        if (w < 4) {
            v8s hc[8];
            #pragma unroll
            for (int ks = 0; ks < 8; ks++) hc[ks] = *(const v8s*)(h2b + hrd[ks]);
            v4f a3 = b3v;
            v4f c3 = {0.f, 0.f, 0.f, 0.f};
            #pragma unroll
            for (int ks = 0; ks < 4; ks++) {
                a3 = __builtin_amdgcn_mfma_f32_16x16x32_bf16(w3f[ks],     hc[ks],     a3, 0, 0, 0);
                c3 = __builtin_amdgcn_mfma_f32_16x16x32_bf16(w3f[ks + 4], hc[ks + 4], c3, 0, 0, 0);
            }
            #pragma unroll
            for (int i = 0; i < 4; i++)
                x[i] = fmaf(a3[i] + c3[i], scale, x[i]);
            uint2 p; p.x = pk2bf(x[0], x[1]); p.y = pk2bf(x[2], x[3]);
            *(uint2*)(xb + xw0) = p;
            *(v4f*)(&tb[s & 3][ln][16 * w + 4 * q]) = x;   // stage sample s+1
        }
        __syncthreads();

        // ---- grouped trajectory flush: coalesced 1KB/row dwordx4 stores.
        // Issued right after the barrier -> overlaps next L1/L2 compute before
        // the next vmcnt drain. 4x fewer drains than per-step stores.
        if ((s & 3) == 3) {
            v4f d0 = *(const v4f*)(trd);
            v4f d1 = *(const v4f*)(trd + 4);
            unsigned ga = gflush + (unsigned)(s - 3) * 64u;
            *(v4f*)(out + ga)     = d0;
            *(v4f*)(out + ga + 4) = d1;
        }
    }

    // ---- tail flush for nsteps % 4 != 0 ----
    int rem = nsteps & 3;
    if (rem && fk < rem) {
        v4f d0 = *(const v4f*)(trd);
        v4f d1 = *(const v4f*)(trd + 4);
        unsigned ga = gflush + (unsigned)(nsteps - rem) * 64u;
        *(v4f*)(out + ga)     = d0;
        *(v4f*)(out + ga + 4) = d1;
    }
}

extern "C" void kernel_launch(void* const* d_in, const int* in_sizes, int n_in,
                              void* d_out, int out_size, void* d_ws, size_t ws_size,
                              hipStream_t stream) {
    const float* x0 = (const float*)d_in[0];
    const float* W1 = (const float*)d_in[1];
    const float* b1 = (const float*)d_in[2];
    const float* W2 = (const float*)d_in[3];
    const float* b2 = (const float*)d_in[4];
    const float* W3 = (const float*)d_in[5];
    const float* b3 = (const float*)d_in[6];
    const float* dt = (const float*)d_in[7];
    const int* steps = (const int*)d_in[8];

    short* W1t = (short*)d_ws;            // 16384 bf16
    short* W2t = W1t + 64 * 256;          // 65536 bf16
    short* W3t = W2t + 256 * 256;         // 16384 bf16

    prep_weights<<<384, 256, 0, stream>>>(W1, W2, W3, W1t, W2t, W3t);
    ode_kernel<<<NBLK, 512, 0, stream>>>(x0, b1, b2, b3, dt, steps,
                                         W1t, W2t, W3t, (float*)d_out);
}

// Round 4
// 433.107 us; speedup vs baseline: 2.2896x; 1.0498x over previous
//
#include <hip/hip_runtime.h>

// NeuralODE: x_{s+1} = x + (tanh(tanh(x W1 + b1) W2 + b2) W3 + b3) * dt_scale * DT
// BATCH=4096, STATE=64, HIDDEN=256, steps=200. Output [4096, 201, 64] fp32.
//
// R7 = EXACT R4 281us skeleton with ONE change: the 3 in-loop __syncthreads()
// are replaced by {s_waitcnt lgkmcnt(0); s_barrier} -- LDS-only sync, no
// vmcnt(0) drain. Trajectory stores (16 scattered lines/wave/step) are never
// read back, so they may retire in the background instead of being force-
// drained at every barrier. Isolation experiment for the store-drain theory.

#define STATE_DIM 64
#define HIDDEN    256
#define TILE_M    16
#define NBLK      256
#define XPITCH    68      // bf16 x pitch (shorts): mult of 4, non-pow2 banking
#define HPITCH    260     // bf16 h pitch (shorts): quads land on distinct banks

typedef short v8s __attribute__((ext_vector_type(8)));
typedef float v4f __attribute__((ext_vector_type(4)));

__device__ __forceinline__ unsigned short f2bf(float f) {
    return (unsigned short)((__float_as_uint(f) + 0x8000u) >> 16);  // round-half-up
}
__device__ __forceinline__ unsigned pk2bf(float a, float b) {
    return ((__float_as_uint(a) + 0x8000u) >> 16) |
           ((__float_as_uint(b) + 0x8000u) & 0xffff0000u);
}
__device__ __forceinline__ float fast_tanh(float x) {
    float e = __builtin_amdgcn_exp2f(x * 2.8853900817779268f);  // exp(2x)
    return 1.0f - 2.0f * __builtin_amdgcn_rcpf(e + 1.0f);
}
// LDS-only barrier: writer-side ds ops drained (lgkmcnt), but global stores
// (trajectory) stay in flight across the barrier. No vmcnt(0) drain.
__device__ __forceinline__ void sync_lds() {
    asm volatile("s_waitcnt lgkmcnt(0)" ::: "memory");
    __builtin_amdgcn_s_barrier();
    asm volatile("" ::: "memory");
}

// ---- prep: fp32 weights -> bf16, transposed to [N][K] ----
__global__ void prep_weights(const float* __restrict__ W1,
                             const float* __restrict__ W2,
                             const float* __restrict__ W3,
                             short* __restrict__ W1t,   // [256][64]
                             short* __restrict__ W2t,   // [256][256]
                             short* __restrict__ W3t) { // [64][256]
    int u = blockIdx.x * 256 + threadIdx.x;
    if (u < 65536) {                       // W2t[n][k] = W2[k][n]
        int n = u >> 8, k = u & 255;
        W2t[u] = (short)f2bf(W2[k * 256 + n]);
    }
    int v = u - 65536;
    if (v >= 0 && v < 16384) {             // W1t[n][k] = W1[k][n]
        int n = v >> 6, k = v & 63;
        W1t[v] = (short)f2bf(W1[k * 256 + n]);
    }
    int t = u - (65536 + 16384);
    if (t >= 0 && t < 16384) {             // W3t[n][k] = W3[k][n]
        int n = t >> 8, k = t & 255;
        W3t[t] = (short)f2bf(W3[k * 64 + n]);
    }
}

__global__ __launch_bounds__(512, 2)
void ode_kernel(const float* __restrict__ x0,
                const float* __restrict__ b1,
                const float* __restrict__ b2,
                const float* __restrict__ b3,
                const float* __restrict__ dt_scale,
                const int*   __restrict__ stepsp,
                const short* __restrict__ W1t,
                const short* __restrict__ W2t,
                const short* __restrict__ W3t,
                float* __restrict__ out) {
    __shared__ short xb [TILE_M * XPITCH];    // bf16 x, B-operand source
    __shared__ short h1b[TILE_M * HPITCH];
    __shared__ short h2b[TILE_M * HPITCH];

    const int tid  = threadIdx.x;
    const int w    = tid >> 6;        // wave 0..7
    const int lane = tid & 63;
    const int ln   = lane & 15;       // batch row (B col / C col)
    const int q    = lane >> 4;
    const int blk  = blockIdx.x;
    const int nsteps = *stepsp;
    const float scale = dt_scale[0] * 0.01f;
    const int n0 = 32 * w;            // this wave's 32 output features (L1/L2)

    // ---- weight A-fragments in registers (A[m=ln][k=32ks+8q+j]) ----
    v8s w1f[2][2], w2f[2][8], w3f[8];
    #pragma unroll
    for (int t = 0; t < 2; t++)
        #pragma unroll
        for (int ks = 0; ks < 2; ks++)
            w1f[t][ks] = *(const v8s*)(W1t + (n0 + 16 * t + ln) * 64 + 32 * ks + 8 * q);
    #pragma unroll
    for (int t = 0; t < 2; t++)
        #pragma unroll
        for (int ks = 0; ks < 8; ks++)
            w2f[t][ks] = *(const v8s*)(W2t + (n0 + 16 * t + ln) * 256 + 32 * ks + 8 * q);
    if (w < 4) {
        #pragma unroll
        for (int ks = 0; ks < 8; ks++)
            w3f[ks] = *(const v8s*)(W3t + (16 * w + ln) * 256 + 32 * ks + 8 * q);
    }
    // ---- biases as per-lane float4 (C rows = feats 4q+i) ----
    v4f b1v[2], b2v[2], b3v = {0.f, 0.f, 0.f, 0.f};
    #pragma unroll
    for (int t = 0; t < 2; t++) {
        b1v[t] = *(const v4f*)(b1 + n0 + 16 * t + 4 * q);
        b2v[t] = *(const v4f*)(b2 + n0 + 16 * t + 4 * q);
    }
    if (w < 4) b3v = *(const v4f*)(b3 + 16 * w + 4 * q);

    // ---- x state in registers of waves 0-3: feats 16w+4q+i, batch ln ----
    v4f x = {0.f, 0.f, 0.f, 0.f};
    unsigned tbase = 0;
    const int xw0 = ln * XPITCH + 16 * w + 4 * q;
    if (w < 4) {
        x = *(const v4f*)(x0 + (size_t)(blk * TILE_M + ln) * STATE_DIM + 16 * w + 4 * q);
        uint2 p; p.x = pk2bf(x[0], x[1]); p.y = pk2bf(x[2], x[3]);
        *(uint2*)(xb + xw0) = p;
        tbase = (unsigned)(blk * TILE_M + ln) * (unsigned)((nsteps + 1) * STATE_DIM)
              + 16 * w + 4 * q;
        *(v4f*)(out + tbase) = x;          // trajectory sample 0
        tbase += STATE_DIM;
    }
    __syncthreads();   // pre-loop: full fence (x0 loads + sample-0 store)

    // ---- hoisted LDS indices ----
    int xrd[2], hrd[8];
    #pragma unroll
    for (int ks = 0; ks < 2; ks++) xrd[ks] = ln * XPITCH + 32 * ks + 8 * q;
    #pragma unroll
    for (int ks = 0; ks < 8; ks++) hrd[ks] = ln * HPITCH + 32 * ks + 8 * q;
    const int hw0 = ln * HPITCH + n0 + 4 * q;   // + 16*t for tile t

    for (int s = 0; s < nsteps; s++) {
        // ---- L1: h1 = tanh(x @ W1 + b1)  (A=W1 frags, B=xb) ----
        v8s xa0 = *(const v8s*)(xb + xrd[0]);
        v8s xa1 = *(const v8s*)(xb + xrd[1]);
        v4f a0 = b1v[0], a1 = b1v[1];
        a0 = __builtin_amdgcn_mfma_f32_16x16x32_bf16(w1f[0][0], xa0, a0, 0, 0, 0);
        a1 = __builtin_amdgcn_mfma_f32_16x16x32_bf16(w1f[1][0], xa0, a1, 0, 0, 0);
        a0 = __builtin_amdgcn_mfma_f32_16x16x32_bf16(w1f[0][1], xa1, a0, 0, 0, 0);
        a1 = __builtin_amdgcn_mfma_f32_16x16x32_bf16(w1f[1][1], xa1, a1, 0, 0, 0);
        {
            uint2 p0, p1;
            p0.x = pk2bf(fast_tanh(a0[0]), fast_tanh(a0[1]));
            p0.y = pk2bf(fast_tanh(a0[2]), fast_tanh(a0[3]));
            p1.x = pk2bf(fast_tanh(a1[0]), fast_tanh(a1[1]));
            p1.y = pk2bf(fast_tanh(a1[2]), fast_tanh(a1[3]));
            *(uint2*)(h1b + hw0)      = p0;
            *(uint2*)(h1b + hw0 + 16) = p1;
        }
        sync_lds();

        // ---- L2: h2 = tanh(h1 @ W2 + b2) ----
        v8s ha[8];
        #pragma unroll
        for (int ks = 0; ks < 8; ks++) ha[ks] = *(const v8s*)(h1b + hrd[ks]);
        a0 = b2v[0]; a1 = b2v[1];
        #pragma unroll
        for (int ks = 0; ks < 8; ks++) {
            a0 = __builtin_amdgcn_mfma_f32_16x16x32_bf16(w2f[0][ks], ha[ks], a0, 0, 0, 0);
            a1 = __builtin_amdgcn_mfma_f32_16x16x32_bf16(w2f[1][ks], ha[ks], a1, 0, 0, 0);
        }
        {
            uint2 p0, p1;
            p0.x = pk2bf(fast_tanh(a0[0]), fast_tanh(a0[1]));
            p0.y = pk2bf(fast_tanh(a0[2]), fast_tanh(a0[3]));
            p1.x = pk2bf(fast_tanh(a1[0]), fast_tanh(a1[1]));
            p1.y = pk2bf(fast_tanh(a1[2]), fast_tanh(a1[3]));
            *(uint2*)(h2b + hw0)      = p0;
            *(uint2*)(h2b + hw0 + 16) = p1;
        }
        sync_lds();

        // ---- L3 + Euler + trajectory store (waves 0-3; 4-7 idle) ----
        if (w < 4) {
            v8s hc[8];
            #pragma unroll
            for (int ks = 0; ks < 8; ks++) hc[ks] = *(const v8s*)(h2b + hrd[ks]);
            v4f a3 = b3v;
            #pragma unroll
            for (int ks = 0; ks < 8; ks++)
                a3 = __builtin_amdgcn_mfma_f32_16x16x32_bf16(w3f[ks], hc[ks], a3, 0, 0, 0);
            #pragma unroll
            for (int i = 0; i < 4; i++)
                x[i] = fmaf(a3[i], scale, x[i]);
            uint2 p; p.x = pk2bf(x[0], x[1]); p.y = pk2bf(x[2], x[3]);
            *(uint2*)(xb + xw0) = p;
            *(v4f*)(out + tbase) = x;      // trajectory sample s+1 (floats free)
            tbase += STATE_DIM;
        }
        sync_lds();
    }
}

extern "C" void kernel_launch(void* const* d_in, const int* in_sizes, int n_in,
                              void* d_out, int out_size, void* d_ws, size_t ws_size,
                              hipStream_t stream) {
    const float* x0 = (const float*)d_in[0];
    const float* W1 = (const float*)d_in[1];
    const float* b1 = (const float*)d_in[2];
    const float* W2 = (const float*)d_in[3];
    const float* b2 = (const float*)d_in[4];
    const float* W3 = (const float*)d_in[5];
    const float* b3 = (const float*)d_in[6];
    const float* dt = (const float*)d_in[7];
    const int* steps = (const int*)d_in[8];

    short* W1t = (short*)d_ws;            // 16384 bf16
    short* W2t = W1t + 64 * 256;          // 65536 bf16
    short* W3t = W2t + 256 * 256;         // 16384 bf16

    prep_weights<<<384, 256, 0, stream>>>(W1, W2, W3, W1t, W2t, W3t);
    ode_kernel<<<NBLK, 512, 0, stream>>>(x0, b1, b2, b3, dt, steps,
                                         W1t, W2t, W3t, (float*)d_out);
}